// Round 7
// baseline (359.348 us; speedup 1.0000x reference)
//
#include <hip/hip_runtime.h>

#define N_NODES 100000
#define NBUCK   782      // ceil(100000/128) buckets of 128 nodes
#define P1TILE  8192     // edges per partition block
#define MAXB    4096     // bucket_csr LDS capacity (avg bucket = 2048 edges)
#define CNTB    256      // blocks doing bucket-count in the fused kernel

typedef __bf16 bf16x8 __attribute__((ext_vector_type(8)));
typedef float floatx4 __attribute__((ext_vector_type(4)));
typedef float floatx2 __attribute__((ext_vector_type(2)));

static __device__ __forceinline__ unsigned short f2bf(float f) {
  unsigned u = __float_as_uint(f);
  u += 0x7fff + ((u >> 16) & 1);   // round-to-nearest-even
  return (unsigned short)(u >> 16);
}

// ===========================================================================
// Fused: bucket-level edge counts (blocks < CNTB) + x -> bf16 convert (rest).
// ===========================================================================
__global__ __launch_bounds__(256) void count_convert_kernel(
    const int* __restrict__ dst, int* __restrict__ bucket_cnt, int n_edges,
    const float* __restrict__ x, unsigned short* __restrict__ xb, int n4) {
  __shared__ int hist[NBUCK];
  if (blockIdx.x < CNTB) {
    for (int b = threadIdx.x; b < NBUCK; b += 256) hist[b] = 0;
    __syncthreads();
    int stride = CNTB * 256;
    for (int e = blockIdx.x * 256 + threadIdx.x; e < n_edges; e += stride)
      atomicAdd(&hist[dst[e] >> 7], 1);
    __syncthreads();
    for (int b = threadIdx.x; b < NBUCK; b += 256) {
      int c = hist[b];
      if (c) atomicAdd(&bucket_cnt[b], c);
    }
  } else {
    int i = (blockIdx.x - CNTB) * 256 + threadIdx.x;
    if (i < n4) {
      float4 v = ((const float4*)x)[i];
      ushort4 o;
      o.x = f2bf(v.x); o.y = f2bf(v.y); o.z = f2bf(v.z); o.w = f2bf(v.w);
      ((ushort4*)xb)[i] = o;
    }
  }
}

// ===========================================================================
// Fused: block 0 = exclusive scan of bucket counts; blocks 1..64 = bf16
// weight transpose (n-major [128 n][128 k], 2 n-rows per block).
// ===========================================================================
__global__ __launch_bounds__(256) void scan_weights_kernel(
    const int* __restrict__ bucket_cnt, int* __restrict__ bucket_base,
    int* __restrict__ bucket_cursor,
    const float* __restrict__ w1_l, const float* __restrict__ w1_r,
    const float* __restrict__ w2_l, const float* __restrict__ w2_r,
    unsigned short* __restrict__ Wt1, unsigned short* __restrict__ Wt2) {
  __shared__ int tmp[256];
  if (blockIdx.x == 0) {
    int t = threadIdx.x;
    int loc[4];
    int s = 0;
    #pragma unroll
    for (int j = 0; j < 4; ++j) {
      int idx = 4 * t + j;
      loc[j] = s;
      s += (idx < NBUCK) ? bucket_cnt[idx] : 0;
    }
    tmp[t] = s;
    __syncthreads();
    for (int off = 1; off < 256; off <<= 1) {
      int u = (t >= off) ? tmp[t - off] : 0;
      __syncthreads();
      tmp[t] += u;
      __syncthreads();
    }
    int excl = tmp[t] - s;
    #pragma unroll
    for (int j = 0; j < 4; ++j) {
      int idx = 4 * t + j;
      if (idx < NBUCK) {
        int v = excl + loc[j];
        bucket_base[idx] = v;
        bucket_cursor[idx] = v;
      }
    }
    if (t == 255) bucket_base[NBUCK] = tmp[255];
  } else {
    int n = (blockIdx.x - 1) * 2 + (threadIdx.x >> 7);
    int k = threadIdx.x & 127;
    float v1 = (n < 64) ? w1_l[k * 64 + n] : w1_r[k * 64 + (n - 64)];
    Wt1[n * 128 + k] = f2bf(v1);
    float v2 = (k < 64) ? w2_l[k * 128 + n] : w2_r[(k - 64) * 128 + n];
    Wt2[n * 128 + k] = f2bf(v2);
  }
}

// ===========================================================================
// Partition (src,dst) pairs into dst-buckets.  LDS histogram + scan +
// reorder per tile so same-bucket pairs leave as contiguous runs.
// ===========================================================================
__global__ __launch_bounds__(256) void bucket_partition_kernel(
    const int* __restrict__ src, const int* __restrict__ dst,
    int* __restrict__ bucket_cursor, int2* __restrict__ pairs, int n_edges) {
  __shared__ int hist[NBUCK];
  __shared__ int scan_[NBUCK];
  __shared__ int gbase[NBUCK];
  __shared__ int tmp[256];
  __shared__ int2 sorted[P1TILE];
  int t = threadIdx.x;
  long e0 = (long)blockIdx.x * P1TILE;
  int n = (int)min((long)P1TILE, (long)n_edges - e0);

  for (int b = t; b < NBUCK; b += 256) hist[b] = 0;
  __syncthreads();
  for (int i = t; i < n; i += 256) atomicAdd(&hist[dst[e0 + i] >> 7], 1);
  __syncthreads();

  int loc[4];
  int s = 0;
  #pragma unroll
  for (int j = 0; j < 4; ++j) {
    int idx = 4 * t + j;
    loc[j] = s;
    s += (idx < NBUCK) ? hist[idx] : 0;
  }
  tmp[t] = s;
  __syncthreads();
  for (int off = 1; off < 256; off <<= 1) {
    int u = (t >= off) ? tmp[t - off] : 0;
    __syncthreads();
    tmp[t] += u;
    __syncthreads();
  }
  int excl = tmp[t] - s;
  #pragma unroll
  for (int j = 0; j < 4; ++j) {
    int idx = 4 * t + j;
    if (idx < NBUCK) scan_[idx] = excl + loc[j];
  }
  __syncthreads();

  for (int b = t; b < NBUCK; b += 256) {
    int c = hist[b];
    gbase[b] = c ? atomicAdd(&bucket_cursor[b], c) : 0;
    hist[b] = scan_[b];
  }
  __syncthreads();

  for (int i = t; i < n; i += 256) {
    int sv = src[e0 + i];
    int dv = dst[e0 + i];
    int r = atomicAdd(&hist[dv >> 7], 1);   // LDS atomic
    sorted[r] = make_int2(sv, dv);
  }
  __syncthreads();

  for (int i = t; i < n; i += 256) {
    int2 p = sorted[i];
    int b = p.y >> 7;
    pairs[gbase[b] + (i - scan_[b])] = p;
  }
}

// ===========================================================================
// Per bucket: node-level CSR offsets (LDS histogram + scan, coalesced write)
// + src values sorted by node (LDS staging, coalesced stream-out).
// ===========================================================================
__global__ __launch_bounds__(256) void bucket_csr_kernel(
    const int2* __restrict__ pairs, const int* __restrict__ bucket_base,
    int* __restrict__ offsets, int* __restrict__ src_sorted,
    int n_nodes, int n_edges) {
  __shared__ int2 sp[MAXB];
  __shared__ int lout[MAXB];
  __shared__ int ndeg[128];
  __shared__ int nsc[128];
  int b = blockIdx.x;
  int node0 = b << 7;
  int t = threadIdx.x;
  int ebeg = bucket_base[b];
  int eend = bucket_base[b + 1];
  int m = eend - ebeg;
  bool fits = (m <= MAXB);
  if (t < 128) ndeg[t] = 0;
  __syncthreads();

  if (fits) {
    for (int i = t; i < m; i += 256) {
      int2 p = pairs[ebeg + i];
      sp[i] = p;
      atomicAdd(&ndeg[p.y & 127], 1);   // LDS atomic
    }
  } else {
    for (int i = t; i < m; i += 256)
      atomicAdd(&ndeg[pairs[ebeg + i].y & 127], 1);
  }
  __syncthreads();

  if (t < 128) nsc[t] = ndeg[t];
  __syncthreads();
  for (int off = 1; off < 128; off <<= 1) {
    int u = 0;
    if (t < 128 && t >= off) u = nsc[t - off];
    __syncthreads();
    if (t < 128) nsc[t] += u;
    __syncthreads();
  }
  if (t < 128) {
    int excl = nsc[t] - ndeg[t];
    int node = node0 + t;
    if (node < n_nodes) offsets[node] = ebeg + excl;
    ndeg[t] = excl;   // repurpose as placement cursor
  }
  if (b == NBUCK - 1 && t == 0) offsets[n_nodes] = n_edges;
  __syncthreads();

  if (fits) {
    for (int i = t; i < m; i += 256) {
      int2 p = sp[i];
      int r = atomicAdd(&ndeg[p.y & 127], 1);  // LDS atomic
      lout[r] = p.x;
    }
    __syncthreads();
    for (int i = t; i < m; i += 256) src_sorted[ebeg + i] = lout[i];
  } else {
    for (int i = t; i < m; i += 256) {
      int2 p = pairs[ebeg + i];
      int r = atomicAdd(&ndeg[p.y & 127], 1);
      src_sorted[ebeg + r] = p.x;
    }
  }
}

// ===========================================================================
// MFMA GEMM: Y[M][128] = A[M][128] @ Wt^T, A bf16, fp32 accum.
// MODE 1 (layer 1): cols 0..63  -> y1 as fp8 e4m3 gather table T8,
//                   cols 64..127 -> z1 = v + b1[col-64] as bf16 into Zb.
// MODE 2 (layer 2): out fp32 = v + bias[col].
// ===========================================================================
template <int MODE>
__global__ __launch_bounds__(256) void mfma_gemm_kernel(
    const unsigned short* __restrict__ A, const unsigned short* __restrict__ Wt,
    const float* __restrict__ bias, float* __restrict__ outf,
    unsigned char* __restrict__ T8, unsigned short* __restrict__ Zb, int M) {
  __shared__ unsigned short As[64 * 136];
  int node0 = blockIdx.x * 64;
  int t = threadIdx.x;
  #pragma unroll
  for (int i = 0; i < 4; ++i) {
    int c = t + i * 256;           // 1024 x 16B chunks
    int row = c >> 4, c8 = (c & 15) * 8;
    uint4 v = make_uint4(0u, 0u, 0u, 0u);
    if (node0 + row < M) v = *(const uint4*)&A[(long)(node0 + row) * 128 + c8];
    *(uint4*)&As[row * 136 + c8] = v;
  }
  __syncthreads();
  int w = t >> 6, lane = t & 63;
  int m = lane & 15, q = lane >> 4;
  int col0 = w * 32;
  floatx4 acc[4][2];
  #pragma unroll
  for (int rt = 0; rt < 4; ++rt)
    #pragma unroll
    for (int ct = 0; ct < 2; ++ct) acc[rt][ct] = (floatx4){0.f, 0.f, 0.f, 0.f};

  #pragma unroll
  for (int ks = 0; ks < 4; ++ks) {
    bf16x8 b0 = *(const bf16x8*)&Wt[(col0 + m) * 128 + ks * 32 + q * 8];
    bf16x8 b1 = *(const bf16x8*)&Wt[(col0 + 16 + m) * 128 + ks * 32 + q * 8];
    #pragma unroll
    for (int rt = 0; rt < 4; ++rt) {
      bf16x8 a = *(const bf16x8*)&As[(rt * 16 + m) * 136 + ks * 32 + q * 8];
      acc[rt][0] = __builtin_amdgcn_mfma_f32_16x16x32_bf16(a, b0, acc[rt][0], 0, 0, 0);
      acc[rt][1] = __builtin_amdgcn_mfma_f32_16x16x32_bf16(a, b1, acc[rt][1], 0, 0, 0);
    }
  }
  // C/D layout (m89-verified): col = lane&15, row = (lane>>4)*4 + reg
  #pragma unroll
  for (int ct = 0; ct < 2; ++ct) {
    int col = col0 + ct * 16 + m;
    if (MODE == 1) {
      if (w < 2) {   // y1 -> fp8 table (wave-uniform branch)
        #pragma unroll
        for (int rt = 0; rt < 4; ++rt)
          #pragma unroll
          for (int i = 0; i < 4; ++i) {
            int row = node0 + rt * 16 + q * 4 + i;
            if (row >= M) continue;
            int p8 = __builtin_amdgcn_cvt_pk_fp8_f32(acc[rt][ct][i], 0.f, 0, false);
            T8[(long)row * 64 + col] = (unsigned char)(p8 & 0xff);
          }
      } else {       // z1 = v + b1 -> bf16
        float bv = bias[col - 64];
        #pragma unroll
        for (int rt = 0; rt < 4; ++rt)
          #pragma unroll
          for (int i = 0; i < 4; ++i) {
            int row = node0 + rt * 16 + q * 4 + i;
            if (row >= M) continue;
            Zb[(long)row * 64 + (col - 64)] = f2bf(acc[rt][ct][i] + bv);
          }
      }
    } else {
      float bv = bias[col];
      #pragma unroll
      for (int rt = 0; rt < 4; ++rt)
        #pragma unroll
        for (int i = 0; i < 4; ++i) {
          int row = node0 + rt * 16 + q * 4 + i;
          if (row >= M) continue;
          outf[(long)row * 128 + col] = acc[rt][ct][i] + bv;
        }
    }
  }
}

// ===========================================================================
// Gather-mean over fp8 rows (64 feats = 64 B).  One wave/node, 4 lanes x
// 16B per edge -> 16 edges in flight; v_cvt_pk_f32_fp8 decode (2 vals/inst),
// float2 accumulation (v_pk_add_f32); shfl-xor combine.
// LAYER1: out = relu(mean + z1) written as bf16 (GEMM2 input) AND fp8 (next
// gather table).  Else: mean -> bf16.
// ===========================================================================
template <bool LAYER1>
__global__ __launch_bounds__(256) void aggregate_fp8_kernel(
    const unsigned char* __restrict__ table, const unsigned short* __restrict__ zadd,
    unsigned short* __restrict__ outb, unsigned char* __restrict__ out8,
    const int* __restrict__ offsets, const int* __restrict__ src_sorted,
    int n_nodes) {
  int wave = (blockIdx.x * 256 + threadIdx.x) >> 6;
  int lane = threadIdx.x & 63;
  if (wave >= n_nodes) return;
  int g = lane >> 2;    // edge slot 0..15
  int l = lane & 3;     // 16B chunk = features [16l, 16l+16)
  int beg = offsets[wave], end = offsets[wave + 1];
  floatx2 acc[8];
  #pragma unroll
  for (int j = 0; j < 8; ++j) acc[j] = (floatx2){0.f, 0.f};
  for (int e = beg + g; e < end; e += 16) {
    int s = src_sorted[e];
    uint4 v = *(const uint4*)&table[(long)s * 64 + l * 16];
    acc[0] += __builtin_amdgcn_cvt_pk_f32_fp8((int)v.x, false);
    acc[1] += __builtin_amdgcn_cvt_pk_f32_fp8((int)v.x, true);
    acc[2] += __builtin_amdgcn_cvt_pk_f32_fp8((int)v.y, false);
    acc[3] += __builtin_amdgcn_cvt_pk_f32_fp8((int)v.y, true);
    acc[4] += __builtin_amdgcn_cvt_pk_f32_fp8((int)v.z, false);
    acc[5] += __builtin_amdgcn_cvt_pk_f32_fp8((int)v.z, true);
    acc[6] += __builtin_amdgcn_cvt_pk_f32_fp8((int)v.w, false);
    acc[7] += __builtin_amdgcn_cvt_pk_f32_fp8((int)v.w, true);
  }
  #pragma unroll
  for (int off = 4; off <= 32; off <<= 1) {
    #pragma unroll
    for (int j = 0; j < 8; ++j) {
      floatx2 o;
      o.x = __shfl_xor(acc[j].x, off, 64);
      o.y = __shfl_xor(acc[j].y, off, 64);
      acc[j] += o;
    }
  }
  if (g != 0) return;
  float inv = 1.f / fmaxf((float)(end - beg), 1.f);
  float r[16];
  #pragma unroll
  for (int j = 0; j < 8; ++j) {
    r[2 * j] = acc[j].x * inv;
    r[2 * j + 1] = acc[j].y * inv;
  }
  if (LAYER1) {
    const uint4* zp = (const uint4*)&zadd[(long)wave * 64 + l * 16];
    uint4 z0 = zp[0], z1 = zp[1];
    unsigned zz[8] = {z0.x, z0.y, z0.z, z0.w, z1.x, z1.y, z1.z, z1.w};
    #pragma unroll
    for (int j = 0; j < 8; ++j) {
      r[2 * j]     = fmaxf(r[2 * j]     + __uint_as_float(zz[j] << 16), 0.f);
      r[2 * j + 1] = fmaxf(r[2 * j + 1] + __uint_as_float(zz[j] & 0xffff0000u), 0.f);
    }
  }
  unsigned op[8];
  #pragma unroll
  for (int j = 0; j < 8; ++j)
    op[j] = (unsigned)f2bf(r[2 * j]) | ((unsigned)f2bf(r[2 * j + 1]) << 16);
  *(uint4*)&outb[(long)wave * 128 + l * 16] =
      make_uint4(op[0], op[1], op[2], op[3]);
  *(uint4*)&outb[(long)wave * 128 + l * 16 + 8] =
      make_uint4(op[4], op[5], op[6], op[7]);
  if (LAYER1) {
    int t0, t1, t2, t3;
    t0 = __builtin_amdgcn_cvt_pk_fp8_f32(r[0], r[1], 0, false);
    t0 = __builtin_amdgcn_cvt_pk_fp8_f32(r[2], r[3], t0, true);
    t1 = __builtin_amdgcn_cvt_pk_fp8_f32(r[4], r[5], 0, false);
    t1 = __builtin_amdgcn_cvt_pk_fp8_f32(r[6], r[7], t1, true);
    t2 = __builtin_amdgcn_cvt_pk_fp8_f32(r[8], r[9], 0, false);
    t2 = __builtin_amdgcn_cvt_pk_fp8_f32(r[10], r[11], t2, true);
    t3 = __builtin_amdgcn_cvt_pk_fp8_f32(r[12], r[13], 0, false);
    t3 = __builtin_amdgcn_cvt_pk_fp8_f32(r[14], r[15], t3, true);
    *(uint4*)&out8[(long)wave * 64 + l * 16] =
        make_uint4((unsigned)t0, (unsigned)t1, (unsigned)t2, (unsigned)t3);
  }
}

extern "C" void kernel_launch(void* const* d_in, const int* in_sizes, int n_in,
                              void* d_out, int out_size, void* d_ws, size_t ws_size,
                              hipStream_t stream) {
  const float* x    = (const float*)d_in[0];
  const int*   ei   = (const int*)d_in[1];
  const float* w1_l = (const float*)d_in[2];
  const float* b1   = (const float*)d_in[3];
  const float* w1_r = (const float*)d_in[4];
  const float* w2_l = (const float*)d_in[5];
  const float* b2   = (const float*)d_in[6];
  const float* w2_r = (const float*)d_in[7];
  float* out = (float*)d_out;

  const int E = in_sizes[1] / 2;
  const int* src = ei;
  const int* dst = ei + E;

  // ---- workspace layout (~71 MB) ----
  unsigned short* ZB2 = (unsigned short*)d_ws;          // [N][128] bf16: xb, then [mean2|h]
  unsigned short* Z1  = ZB2 + (long)N_NODES * 128;      // [N][64] bf16: z1
  unsigned short* Wt1 = Z1 + (long)N_NODES * 64;        // 128x128 bf16
  unsigned short* Wt2 = Wt1 + 16384;                    // 128x128 bf16
  unsigned char* T1  = (unsigned char*)(Wt2 + 16384);   // [N][64] fp8: y1 table
  unsigned char* T2  = T1 + (long)N_NODES * 64;         // [N][64] fp8: h table
  int* bucket_cnt    = (int*)(T2 + (long)N_NODES * 64); // 782 (even)
  int* bucket_base   = bucket_cnt + NBUCK;              // 784 (padded even)
  int* bucket_cursor = bucket_base + NBUCK + 2;         // 784 (padded even)
  int* offsets       = bucket_cursor + NBUCK + 2;       // N+2 (even)
  int* src_sorted    = offsets + N_NODES + 2;           // E (even)
  int2* pairs        = (int2*)(src_sorted + E);         // E int2 (8B-aligned)

  const int n4 = N_NODES * 128 / 4;

  // ---- CSR build + bf16 prep (fused where independent) ----
  hipMemsetAsync(bucket_cnt, 0, (size_t)NBUCK * sizeof(int), stream);
  count_convert_kernel<<<CNTB + (n4 + 255) / 256, 256, 0, stream>>>(
      dst, bucket_cnt, E, x, ZB2, n4);
  scan_weights_kernel<<<65, 256, 0, stream>>>(
      bucket_cnt, bucket_base, bucket_cursor, w1_l, w1_r, w2_l, w2_r, Wt1, Wt2);
  bucket_partition_kernel<<<(E + P1TILE - 1) / P1TILE, 256, 0, stream>>>(
      src, dst, bucket_cursor, pairs, E);
  bucket_csr_kernel<<<NBUCK, 256, 0, stream>>>(pairs, bucket_base, offsets,
                                               src_sorted, N_NODES, E);

  int gemm_blocks = (N_NODES + 63) / 64;
  int agg_blocks = (N_NODES + 3) / 4;

  // ---- Layer 1: y1 -> T1 (fp8), z1 = x@w1_r + b1 -> Z1 (bf16) ----
  mfma_gemm_kernel<1><<<gemm_blocks, 256, 0, stream>>>(
      ZB2, Wt1, b1, nullptr, T1, Z1, N_NODES);
  // h = relu(mean(y1) + z1) -> ZB2[:,64:128] (bf16) + T2 (fp8)
  aggregate_fp8_kernel<true><<<agg_blocks, 256, 0, stream>>>(
      T1, Z1, ZB2 + 64, T2, offsets, src_sorted, N_NODES);

  // ---- Layer 2: mean2 -> ZB2[:,0:64]; out = [mean2|h] @ Wt2^T + b2 ----
  aggregate_fp8_kernel<false><<<agg_blocks, 256, 0, stream>>>(
      T2, nullptr, ZB2, nullptr, offsets, src_sorted, N_NODES);
  mfma_gemm_kernel<2><<<gemm_blocks, 256, 0, stream>>>(
      ZB2, Wt2, b2, out, nullptr, nullptr, N_NODES);
}